// Round 2
// baseline (919.642 us; speedup 1.0000x reference)
//
#include <hip/hip_runtime.h>
#include <stdint.h>

typedef float f32x4 __attribute__((ext_vector_type(4)));
typedef short s16x8 __attribute__((ext_vector_type(8)));

// ---- problem constants ----
#define E_N 3
#define F_N 4
#define HO_N 111
#define WO_N 111
#define PQR_N 125

#define M_TOT 147852      // 4*111*111*3
#define K_TOT 288         // 8*3*3*4

// x strides (floats): [4,8,224,224,3,4]
#define XS_E 4
#define XS_W 12
#define XS_H 2688
#define XS_C 602112
#define XS_B 4816896

// w strides (floats): [4,8,3,3,4,5,5,5]; (c,kh,kw) collapse to grp*500
#define WS_G 36000

// out strides (floats): [4,4,111,111,3,125]
#define OS_E 125
#define OS_J 375
#define OS_I 41625
#define OS_G 4620375
#define OS_B 18481500

__device__ __forceinline__ unsigned short f2bf(float f) {
  uint32_t u = __float_as_uint(f);
  u += 0x7FFFu + ((u >> 16) & 1u);   // round-to-nearest-even
  return (unsigned short)(u >> 16);
}

// GEMM: C[M=147852, N=512pad] = A[M,288] * B[288,512], bf16 inputs, fp32 acc.
// A[m,k] = x[b,c,2i+kh,2j+kw,e,f], m=(b,i,j,e) e-fastest; k=((c*3+kh)*3+kw)*4+f.
// B[k,n] = w[g,c,kh,kw,f,pqr], n = g*128 + pqr (pqr>=125 zero-padded).
// Block: 128(M) x 64(N); 4 waves 2x2; wave = 64x32 = 4x2 frags of 16x16.
// MFMA 16x16x32_bf16 layouts (guide-verified): A/B lane: row=l&15, k=8*(l>>4)+j
// (8 contiguous bf16 -> ds_read_b128); C/D: col=l&15, row=4*(l>>4)+reg.
__global__ __launch_bounds__(256, 2)
void conv_mfma_kernel(const float* __restrict__ x,
                      const float* __restrict__ w,
                      float* __restrict__ out) {
  __shared__ unsigned short Bs[64][296];     // [n'][k], full K resident, 37,888 B
  __shared__ unsigned short As[2][128][40];  // double-buffered K-step, 20,480 B
  __shared__ uint32_t rowBase[128];          // per-row x float-offset

  const int t    = threadIdx.x;
  const int bid  = blockIdx.x;
  const int nt   = bid & 7;      // 8 N-tiles share one A-tile (L2 locality)
  const int mt   = bid >> 3;
  const int g    = nt >> 1;
  const int poff = (nt & 1) * 64;

  // ---- per-row x base offsets ----
  if (t < 128) {
    int m = mt * 128 + t;
    if (m >= M_TOT) m = M_TOT - 1;           // clamp: safe reads, store skipped
    int e = m % 3;      int t1 = m / 3;
    int j = t1 % WO_N;  int t2 = t1 / WO_N;
    int i = t2 % HO_N;  int b  = t2 / HO_N;
    rowBase[t] = (uint32_t)(b * XS_B + (2 * i) * XS_H + (2 * j) * XS_W + e * XS_E);
  }

  // ---- stage full-K B tile: Bs[n'][k] = w[g, grp(k), f(k), poff+n'] ----
  for (int s = 0; s < 72; ++s) {
    int lin  = s * 256 + t;
    int np   = lin & 63;        // n' (pqr fastest -> coalesced)
    int kidx = lin >> 6;        // 0..287
    int pq   = poff + np;
    float val = 0.0f;
    if (pq < PQR_N) {
      int grp = kidx >> 2;      // c*9 + kh*3 + kw
      int f   = kidx & 3;
      val = w[g * WS_G + grp * 500 + f * 125 + pq];
    }
    Bs[np][kidx] = f2bf(val);
  }

  __syncthreads();  // rowBase visible for A staging

  const int lane = t & 63;
  const int wv   = t >> 6;
  const int wr   = wv >> 1;           // wave row 0..1 (64 rows each)
  const int wc   = wv & 1;            // wave col 0..1 (32 cols each)
  const int l15  = lane & 15;
  const int k0   = (lane >> 4) * 8;   // k-offset within 32-step

  // ---- A stage for ks=0 ----
  {
    #pragma unroll
    for (int it = 0; it < 2; ++it) {
      int lin = it * 256 + t;
      int r   = lin & 127;
      int gp  = lin >> 7;             // 0..3 (pair of k-groups)
      uint32_t rb = rowBase[r];
      s16x8 hh;
      #pragma unroll
      for (int u = 0; u < 2; ++u) {
        int gg = 0 * 8 + gp * 2 + u;
        int c  = gg / 9;
        int r9 = gg - c * 9;
        int kh = r9 / 3;
        int kw = r9 - kh * 3;
        const f32x4 v = *(const f32x4*)(x + rb + c * XS_C + kh * XS_H + kw * XS_W);
        hh[u * 4 + 0] = (short)f2bf(v[0]);
        hh[u * 4 + 1] = (short)f2bf(v[1]);
        hh[u * 4 + 2] = (short)f2bf(v[2]);
        hh[u * 4 + 3] = (short)f2bf(v[3]);
      }
      *(s16x8*)&As[0][r][gp * 8] = hh;
    }
  }
  __syncthreads();

  f32x4 acc[4][2];
  #pragma unroll
  for (int mf = 0; mf < 4; ++mf)
    #pragma unroll
    for (int nf = 0; nf < 2; ++nf)
      acc[mf][nf] = (f32x4){0.f, 0.f, 0.f, 0.f};

  // ---- K loop: 9 steps of 32 ----
  for (int ks = 0; ks < 9; ++ks) {
    const int cur = ks & 1;

    // prefetch next step's gather into regs (issued before MFMA cluster)
    f32x4 pv[4];
    if (ks < 8) {
      #pragma unroll
      for (int it = 0; it < 2; ++it) {
        int lin = it * 256 + t;
        int r   = lin & 127;
        int gp  = lin >> 7;
        uint32_t rb = rowBase[r];
        #pragma unroll
        for (int u = 0; u < 2; ++u) {
          int gg = (ks + 1) * 8 + gp * 2 + u;
          int c  = gg / 9;
          int r9 = gg - c * 9;
          int kh = r9 / 3;
          int kw = r9 - kh * 3;
          pv[it * 2 + u] = *(const f32x4*)(x + rb + c * XS_C + kh * XS_H + kw * XS_W);
        }
      }
    }

    // fragment reads + MFMA
    s16x8 af[4], bf[2];
    #pragma unroll
    for (int mf = 0; mf < 4; ++mf)
      af[mf] = *(const s16x8*)&As[cur][wr * 64 + mf * 16 + l15][k0];
    #pragma unroll
    for (int nf = 0; nf < 2; ++nf)
      bf[nf] = *(const s16x8*)&Bs[wc * 32 + nf * 16 + l15][ks * 32 + k0];
    #pragma unroll
    for (int mf = 0; mf < 4; ++mf)
      #pragma unroll
      for (int nf = 0; nf < 2; ++nf)
        acc[mf][nf] = __builtin_amdgcn_mfma_f32_16x16x32_bf16(af[mf], bf[nf], acc[mf][nf], 0, 0, 0);

    // convert + write next buffer
    if (ks < 8) {
      #pragma unroll
      for (int it = 0; it < 2; ++it) {
        int lin = it * 256 + t;
        int r   = lin & 127;
        int gp  = lin >> 7;
        s16x8 hh;
        #pragma unroll
        for (int u = 0; u < 2; ++u) {
          f32x4 v = pv[it * 2 + u];
          hh[u * 4 + 0] = (short)f2bf(v[0]);
          hh[u * 4 + 1] = (short)f2bf(v[1]);
          hh[u * 4 + 2] = (short)f2bf(v[2]);
          hh[u * 4 + 3] = (short)f2bf(v[3]);
        }
        *(s16x8*)&As[cur ^ 1][r][gp * 8] = hh;
      }
    }
    __syncthreads();
  }

  // ---- epilogue: scatter to out[b,g,i,j,e,pqr] ----
  const int colbase = wc * 32 + l15;
  const int rq = (lane >> 4) * 4;
  #pragma unroll
  for (int mf = 0; mf < 4; ++mf) {
    #pragma unroll
    for (int q = 0; q < 4; ++q) {
      int m = mt * 128 + wr * 64 + mf * 16 + rq + q;
      if (m < M_TOT) {
        int e = m % 3;      int t1 = m / 3;
        int j = t1 % WO_N;  int t2 = t1 / WO_N;
        int i = t2 % HO_N;  int b  = t2 / HO_N;
        int ob = b * OS_B + g * OS_G + i * OS_I + j * OS_J + e * OS_E + poff;
        #pragma unroll
        for (int nf = 0; nf < 2; ++nf) {
          int col = colbase + nf * 16;          // 0..63 within N-tile
          if (poff + col < PQR_N)
            out[ob + col] = acc[mf][nf][q];
        }
      }
    }
  }
}

extern "C" void kernel_launch(void* const* d_in, const int* in_sizes, int n_in,
                              void* d_out, int out_size, void* d_ws, size_t ws_size,
                              hipStream_t stream) {
  const float* x  = (const float*)d_in[0];
  const float* w  = (const float*)d_in[1];
  float* out      = (float*)d_out;

  const int mtiles = (M_TOT + 127) / 128;   // 1156
  dim3 grid(mtiles * 8);                    // 8 N-tiles (4 g x 2 pqr-halves)
  conv_mfma_kernel<<<grid, 256, 0, stream>>>(x, w, out);
}